// Round 5
// baseline (228.226 us; speedup 1.0000x reference)
//
#include <hip/hip_runtime.h>

// SigMMDLoss, algebraically flattened (see round-1/2 derivation):
//   A  = p[4095]-p[0]; S3 = p[4095] - SP_row/n; S4 = (A^2+S6)/2;
//   S6 = sum d^2; S8 = sum d^3;  time-only features cancel.
// Global sums per array: SP (sum p excl last col), D2, D3,
// G1 = sum_rows A, G2 = sum_rows A^2, G3 = sum_rows p[4095].
// out = sum_q ((F_q^real - F_q^gen)/B)^2.
//
// Round-8: copy-kernel structure. Round-7's explicit 16-float4 double
// buffer + serial carry chain spilled to scratch under the 64-VGPR cap
// (WRITE_SIZE 0.8 -> 183 MB) -- the fix is NOT deep batching (32 waves/CU
// x 1 KB in flight already covers the latency-BW product) but a small
// live set with fully independent iterations:
//  - lane 0's predecessor comes from a 1-dword uniform load rp[i*256-1]
//    (L1/L2-hit, same line as the previous chunk) -- no serial carry.
//  - one wave = one row, 16 chunks in 4 groups of 4; ~20 staging VGPRs.
//  - the only cross-lane op is one independent rotate-bpermute per chunk.

constexpr int T_LEN = 4096;
constexpr int B_ROWS = 4096;
constexpr int NQ = 6;                   // sp, d2, d3, g1, g2, g3
constexpr int NBLK = 2048;

__global__ __launch_bounds__(256, 8) void sig_row(
    const float* __restrict__ real, const float* __restrict__ gen,
    double* __restrict__ P) {
  const int tid = threadIdx.x;
  const int lane = tid & 63;
  const int wid = tid >> 6;
  const int w = blockIdx.x * 4 + wid;       // wave id in [0, 8192)
  const int which = w >> 12;                // 0: real rows, 1: gen rows
  const int row = w & 4095;
  const float* __restrict__ rp = (which ? gen : real) + (size_t)row * T_LEN;
  const float4* __restrict__ q4 = reinterpret_cast<const float4*>(rp);
  const int rsrc = (lane + 63) & 63;        // rotate-by-1 source lane

  float sp = 0.f, s2 = 0.f, s3 = 0.f;
  float p0 = 0.f, plast = 0.f;

  // One chunk = 256 floats (one float4/lane). predv = predecessor of the
  // chunk's first element (only lane 0 consumes it).
  auto acc1 = [&](const float4& v, float predv) {
    const float rot = __shfl(v.w, rsrc, 64);
    const float px = (lane == 0) ? predv : rot;
    const float d0 = v.x - px;
    const float d1 = v.y - v.x;
    const float d2 = v.z - v.y;
    const float d3 = v.w - v.z;
    const float e0 = d0 * d0, e1 = d1 * d1, e2 = d2 * d2, e3 = d3 * d3;
    s2 += (e0 + e1) + (e2 + e3);
    s3 += (e0 * d0 + e1 * d1) + (e2 * d2 + e3 * d3);
    sp += (v.x + v.y) + (v.z + v.w);
  };

#pragma unroll
  for (int g = 0; g < 4; ++g) {
    const int i0 = g * 4;
    const float4 v0 = q4[(i0 + 0) * 64 + lane];
    const float4 v1 = q4[(i0 + 1) * 64 + lane];
    const float4 v2 = q4[(i0 + 2) * 64 + lane];
    const float4 v3 = q4[(i0 + 3) * 64 + lane];
    // Wave-uniform predecessor dwords (1 line request each, L1/L2-hot).
    const float q0p = rp[i0 == 0 ? 0 : i0 * 256 - 1];  // i=0: d0=0 at t=0
    const float q1p = rp[(i0 + 1) * 256 - 1];
    const float q2p = rp[(i0 + 2) * 256 - 1];
    const float q3p = rp[(i0 + 3) * 256 - 1];
    if (g == 0) p0 = q0p;                   // p[row][0]
    acc1(v0, q0p);
    acc1(v1, q1p);
    acc1(v2, q2p);
    acc1(v3, q3p);
    if (g == 3) plast = v3.w;               // lane 63: p[row][4095]
  }

  // Row-level features on lane 63 (holds p[4095]).
  double g1 = 0., g2 = 0., g3 = 0.;
  if (lane == 63) {
    sp -= plast;                            // SP excludes last column
    const double A = (double)plast - (double)p0;
    g1 = A;
    g2 = A * A;
    g3 = (double)plast;
  }

  // Wave reduce (fp32 streams; g* already single-lane).
#pragma unroll
  for (int o = 32; o; o >>= 1) {
    sp += __shfl_down(sp, o, 64);
    s2 += __shfl_down(s2, o, 64);
    s3 += __shfl_down(s3, o, 64);
  }

  const double sgn = which ? -1.0 : 1.0;    // fold real-minus-gen here
  __shared__ double sred[4][NQ];
  if (lane == 0) {
    sred[wid][0] = sgn * (double)sp;
    sred[wid][1] = sgn * (double)s2;
    sred[wid][2] = sgn * (double)s3;
  }
  if (lane == 63) {
    sred[wid][3] = sgn * g1;
    sred[wid][4] = sgn * g2;
    sred[wid][5] = sgn * g3;
  }
  __syncthreads();
  if (tid < NQ) {
    const double s = sred[0][tid] + sred[1][tid] + sred[2][tid] + sred[3][tid];
    P[tid * NBLK + blockIdx.x] = s;
  }
}

__global__ __launch_bounds__(1024) void sig_final(const double* __restrict__ P,
                                                  float* __restrict__ out) {
  const int tid = threadIdx.x;
  double loc[NQ] = {0, 0, 0, 0, 0, 0};
  for (int i = tid; i < NBLK; i += 1024) {
#pragma unroll
    for (int q = 0; q < NQ; ++q) loc[q] += P[q * NBLK + i];
  }
#pragma unroll
  for (int q = 0; q < NQ; ++q)
#pragma unroll
    for (int o = 32; o; o >>= 1) loc[q] += __shfl_down(loc[q], o, 64);

  __shared__ double sred[16][NQ];
  const int lane = tid & 63, wid = tid >> 6;
  if (lane == 0)
#pragma unroll
    for (int q = 0; q < NQ; ++q) sred[wid][q] = loc[q];
  __syncthreads();
  if (tid == 0) {
    double Q[NQ];
#pragma unroll
    for (int q = 0; q < NQ; ++q) {
      double s = 0.;
      for (int v = 0; v < 16; ++v) s += sred[v][q];
      Q[q] = s;
    }
    const double n = (double)(T_LEN - 1), Bn = (double)B_ROWS;
    const double FA = Q[3] / Bn;
    const double FS3 = (Q[5] - Q[0] / n) / Bn;
    const double FS4 = 0.5 * (Q[4] + Q[1]) / Bn;
    const double FS6 = Q[1] / Bn;
    const double FS8 = Q[2] / Bn;
    const double o = FA * FA + FS3 * FS3 + FS4 * FS4 + FS6 * FS6 + FS8 * FS8;
    out[0] = (float)o;
  }
}

extern "C" void kernel_launch(void* const* d_in, const int* in_sizes, int n_in,
                              void* d_out, int out_size, void* d_ws, size_t ws_size,
                              hipStream_t stream) {
  const float* real = (const float*)d_in[0];
  const float* gen = (const float*)d_in[1];
  double* P = (double*)d_ws;            // NQ * NBLK * 8 = 96 KB
  float* out = (float*)d_out;

  sig_row<<<NBLK, 256, 0, stream>>>(real, gen, P);
  sig_final<<<1, 1024, 0, stream>>>(P, out);
}

// Round 6
// 152.302 us; speedup vs baseline: 1.4985x; 1.4985x over previous
//
#include <hip/hip_runtime.h>

// SigMMDLoss, algebraically flattened (see round-1/2 derivation):
//   A  = p[4095]-p[0]; S3 = p[4095] - SP_row/n; S4 = (A^2+S6)/2;
//   S6 = sum d^2; S8 = sum d^3;  time-only features cancel.
// Global sums per array: SP (sum p excl last col), D2, D3,
// G1 = sum_rows A, G2 = sum_rows A^2, G3 = sum_rows p[4095].
// out = sum_q ((F_q^real - F_q^gen)/B)^2.
//
// Round-9: loop-not-burst + tail-free waves.
//  * All prior rounds plateaued at ~3 TB/s demand: one-shot load bursts
//    leave each wave with zero loads outstanding during compute/reduce/
//    teardown (~60% of its life) -> ~40% memory duty cycle.
//  * Round-8's full 16-chunk unroll let the scheduler hoist all loads,
//    blowing the 64-VGPR cap -> 200 MB scratch spill (WRITE_SIZE).
//  * Now: one wave = one row, `#pragma unroll 1` loop of 4 groups x
//    4 float4 (live set ~32 VGPR, no cross-iteration hoisting, loads in
//    flight for the wave's whole life), and NO LDS/barrier tail - each
//    wave writes its own 6 signed partials; the finalizer sums 8192.

constexpr int T_LEN = 4096;
constexpr int B_ROWS = 4096;
constexpr int NQ = 6;                   // sp, d2, d3, g1, g2, g3
constexpr int NWAVE = 8192;             // 4096 rows x 2 arrays
constexpr int NBLK = NWAVE / 4;         // 2048 blocks, 4 waves each

__global__ __launch_bounds__(256, 8) void sig_row2(
    const float* __restrict__ real, const float* __restrict__ gen,
    double* __restrict__ P) {
  const int tid = threadIdx.x;
  const int lane = tid & 63;
  const int wid = tid >> 6;
  const int w = blockIdx.x * 4 + wid;       // wave id in [0, 8192)
  const int which = w >> 12;                // 0: real rows, 1: gen rows
  const int row = w & 4095;
  const float* __restrict__ rp = (which ? gen : real) + (size_t)row * T_LEN;
  const float4* __restrict__ q4 = reinterpret_cast<const float4*>(rp);
  const int rsrc = (lane + 63) & 63;        // rotate-by-1 source lane

  float sp = 0.f, s2 = 0.f, s3 = 0.f;
  float p0 = 0.f, plast = 0.f;

  // One chunk = 256 floats (one float4/lane). predv = predecessor of the
  // chunk's first element (only lane 0 consumes it); pred comes from a
  // wave-uniform 1-dword load of a line fetched moments ago (L1-hot).
  auto acc1 = [&](const float4& v, float predv) {
    const float rot = __shfl(v.w, rsrc, 64);
    const float px = (lane == 0) ? predv : rot;
    const float d0 = v.x - px;
    const float d1 = v.y - v.x;
    const float d2 = v.z - v.y;
    const float d3 = v.w - v.z;
    const float e0 = d0 * d0, e1 = d1 * d1, e2 = d2 * d2, e3 = d3 * d3;
    s2 += (e0 + e1) + (e2 + e3);
    s3 += (e0 * d0 + e1 * d1) + (e2 * d2 + e3 * d3);
    sp += (v.x + v.y) + (v.z + v.w);
  };

#pragma unroll 1
  for (int g = 0; g < 4; ++g) {
    const int i0 = g * 4;
    const float4 v0 = q4[(i0 + 0) * 64 + lane];
    const float4 v1 = q4[(i0 + 1) * 64 + lane];
    const float4 v2 = q4[(i0 + 2) * 64 + lane];
    const float4 v3 = q4[(i0 + 3) * 64 + lane];
    const float q0p = rp[i0 ? i0 * 256 - 1 : 0];  // i=0: d0=0 at t=0
    const float q1p = rp[(i0 + 1) * 256 - 1];
    const float q2p = rp[(i0 + 2) * 256 - 1];
    const float q3p = rp[(i0 + 3) * 256 - 1];
    if (g == 0) p0 = q0p;                   // p[row][0]
    acc1(v0, q0p);
    acc1(v1, q1p);
    acc1(v2, q2p);
    acc1(v3, q3p);
    if (g == 3) plast = v3.w;               // lane 63: p[row][4095]
  }

  // Row-level features on lane 63 (holds p[4095]).
  double g1 = 0., g2 = 0., g3 = 0.;
  if (lane == 63) {
    sp -= plast;                            // SP excludes last column
    const double A = (double)plast - (double)p0;
    g1 = A;
    g2 = A * A;
    g3 = (double)plast;
  }

  // Wave reduce (fp32 streams; g* already single-lane on lane 63).
#pragma unroll
  for (int o = 32; o; o >>= 1) {
    sp += __shfl_down(sp, o, 64);
    s2 += __shfl_down(s2, o, 64);
    s3 += __shfl_down(s3, o, 64);
  }

  // Tail-free: each wave writes its own signed partials. No LDS/barrier.
  const double sgn = which ? -1.0 : 1.0;    // fold real-minus-gen here
  if (lane == 0) {
    P[0 * NWAVE + w] = sgn * (double)sp;
    P[1 * NWAVE + w] = sgn * (double)s2;
    P[2 * NWAVE + w] = sgn * (double)s3;
  }
  if (lane == 63) {
    P[3 * NWAVE + w] = sgn * g1;
    P[4 * NWAVE + w] = sgn * g2;
    P[5 * NWAVE + w] = sgn * g3;
  }
}

__global__ __launch_bounds__(1024) void sig_final(const double* __restrict__ P,
                                                  float* __restrict__ out) {
  const int tid = threadIdx.x;
  double loc[NQ] = {0, 0, 0, 0, 0, 0};
  for (int i = tid; i < NWAVE; i += 1024) {
#pragma unroll
    for (int q = 0; q < NQ; ++q) loc[q] += P[q * NWAVE + i];
  }
#pragma unroll
  for (int q = 0; q < NQ; ++q)
#pragma unroll
    for (int o = 32; o; o >>= 1) loc[q] += __shfl_down(loc[q], o, 64);

  __shared__ double sred[16][NQ];
  const int lane = tid & 63, wid = tid >> 6;
  if (lane == 0)
#pragma unroll
    for (int q = 0; q < NQ; ++q) sred[wid][q] = loc[q];
  __syncthreads();
  if (tid == 0) {
    double Q[NQ];
#pragma unroll
    for (int q = 0; q < NQ; ++q) {
      double s = 0.;
      for (int v = 0; v < 16; ++v) s += sred[v][q];
      Q[q] = s;
    }
    const double n = (double)(T_LEN - 1), Bn = (double)B_ROWS;
    const double FA = Q[3] / Bn;
    const double FS3 = (Q[5] - Q[0] / n) / Bn;
    const double FS4 = 0.5 * (Q[4] + Q[1]) / Bn;
    const double FS6 = Q[1] / Bn;
    const double FS8 = Q[2] / Bn;
    const double o = FA * FA + FS3 * FS3 + FS4 * FS4 + FS6 * FS6 + FS8 * FS8;
    out[0] = (float)o;
  }
}

extern "C" void kernel_launch(void* const* d_in, const int* in_sizes, int n_in,
                              void* d_out, int out_size, void* d_ws, size_t ws_size,
                              hipStream_t stream) {
  const float* real = (const float*)d_in[0];
  const float* gen = (const float*)d_in[1];
  double* P = (double*)d_ws;            // NQ * NWAVE * 8 = 384 KB
  float* out = (float*)d_out;

  sig_row2<<<NBLK, 256, 0, stream>>>(real, gen, P);
  sig_final<<<1, 1024, 0, stream>>>(P, out);
}

// Round 7
// 149.985 us; speedup vs baseline: 1.5217x; 1.0154x over previous
//
#include <hip/hip_runtime.h>

// SigMMDLoss, algebraically flattened:
//   A  = p[4095]-p[0]; S3 = p[4095] - SP_row/n; S4 = (A^2+S6)/2;
//   S6 = sum d^2; S8 = sum d^3;  time-only features cancel.
//
// Round-10: copy-shaped streaming. Rounds 1-9 all plateaued at ~3 TB/s
// demand with wave-owns-a-row mapping (8192 scattered 16 KB streams ->
// poor DRAM page locality). Now grid-strided flat spans: span s (256
// elems) -> wave (s%4096) at iter (s/4096), so each iteration the whole
// GPU sweeps ONE contiguous 4 MB window per array (the m13 copy-kernel
// pattern that hits 6.3 TB/s). Row coupling dissolved:
//  - 16 spans/row and stride 4096 => wa%16 is loop-invariant: a wave is
//    permanently row-start (d0=0, pred=self), row-end (computes A via one
//    extra uniform p0 load; lane63 holds p_last), or interior.
//  - SP excl last col recovered in finalizer: SP_excl = Q_sp - Q_g3.
// Partials: block LDS-reduce -> 6 doubles/block (sign folded).

constexpr int T_LEN = 4096;
constexpr int B_ROWS = 4096;
constexpr int NQ = 6;                   // sp_all, d2, d3, g1, g2, g3
constexpr int NBLK = 2048;              // 4 waves/block -> 8192 waves
constexpr int WPA = 4096;               // waves per array
constexpr int ITERS = (B_ROWS * T_LEN / 256) / WPA;  // 65536 spans / 4096 = 16

__global__ __launch_bounds__(256, 8) void sig_fstream(
    const float* __restrict__ real, const float* __restrict__ gen,
    double* __restrict__ P) {
  const int tid = threadIdx.x;
  const int lane = tid & 63;
  const int wid = tid >> 6;
  const int gw = blockIdx.x * 4 + wid;      // global wave id [0, 8192)
  const int which = gw >> 12;               // 0: real, 1: gen
  const int wa = gw & 4095;                 // wave id within array
  const float* __restrict__ base = which ? gen : real;
  const int rsrc = (lane + 63) & 63;        // rotate-by-1 source lane
  const int mode = wa & 15;                 // 0: row-start spans; 15: row-end

  float sp = 0.f, s2 = 0.f, s3 = 0.f;
  double g1 = 0., g2 = 0., g3 = 0.;

#pragma unroll 2
  for (int it = 0; it < ITERS; ++it) {
    // span index s = wa + it*4096; all waves sweep a contiguous 4 MB
    // window together each iteration (copy-kernel locality).
    const float* __restrict__ spp = base + ((size_t)wa + (size_t)it * WPA) * 256;
    const float4 v = reinterpret_cast<const float4*>(spp)[lane];
    // Predecessor of span's first element (only lane 0 uses it). Row-start
    // spans use v.x itself (d0 = 0 at t=0) - no load. Interior/row-end
    // spans: 1 uniform dword from the line just read by the previous wave.
    float pm = 0.f;
    if (mode != 0) pm = spp[-1];
    const float rot = __shfl(v.w, rsrc, 64);
    const float px = (lane == 0) ? (mode == 0 ? v.x : pm) : rot;
    const float d0 = v.x - px;
    const float d1 = v.y - v.x;
    const float d2 = v.z - v.y;
    const float d3 = v.w - v.z;
    const float e0 = d0 * d0, e1 = d1 * d1, e2 = d2 * d2, e3 = d3 * d3;
    s2 += (e0 + e1) + (e2 + e3);
    s3 += (e0 * d0 + e1 * d1) + (e2 * d2 + e3 * d3);
    sp += (v.x + v.y) + (v.z + v.w);
    if (mode == 15) {
      // This span is elements [3840,4096) of row r = s/16; p0 = spp[-3840].
      const float p0r = spp[-3840];
      if (lane == 63) {                     // v.w = p[r][4095]
        const double A = (double)v.w - (double)p0r;
        g1 += A;
        g2 += A * A;
        g3 += (double)v.w;
      }
    }
  }

  // Wave reduce (fp32 streams; g* live on lane 63 of mode-15 waves only).
#pragma unroll
  for (int o = 32; o; o >>= 1) {
    sp += __shfl_down(sp, o, 64);
    s2 += __shfl_down(s2, o, 64);
    s3 += __shfl_down(s3, o, 64);
  }

  const double sgn = which ? -1.0 : 1.0;    // fold real-minus-gen here
  __shared__ double sred[4][NQ];
  if (lane == 0) {
    sred[wid][0] = sgn * (double)sp;
    sred[wid][1] = sgn * (double)s2;
    sred[wid][2] = sgn * (double)s3;
  }
  if (lane == 63) {                         // zeros from non-row-end waves
    sred[wid][3] = sgn * g1;
    sred[wid][4] = sgn * g2;
    sred[wid][5] = sgn * g3;
  }
  __syncthreads();
  if (tid < NQ) {
    const double s = sred[0][tid] + sred[1][tid] + sred[2][tid] + sred[3][tid];
    P[tid * NBLK + blockIdx.x] = s;
  }
}

__global__ __launch_bounds__(1024) void sig_final(const double* __restrict__ P,
                                                  float* __restrict__ out) {
  const int tid = threadIdx.x;
  double loc[NQ] = {0, 0, 0, 0, 0, 0};
  for (int i = tid; i < NBLK; i += 1024) {
#pragma unroll
    for (int q = 0; q < NQ; ++q) loc[q] += P[q * NBLK + i];
  }
#pragma unroll
  for (int q = 0; q < NQ; ++q)
#pragma unroll
    for (int o = 32; o; o >>= 1) loc[q] += __shfl_down(loc[q], o, 64);

  __shared__ double sred[16][NQ];
  const int lane = tid & 63, wid = tid >> 6;
  if (lane == 0)
#pragma unroll
    for (int q = 0; q < NQ; ++q) sred[wid][q] = loc[q];
  __syncthreads();
  if (tid == 0) {
    double Q[NQ];
#pragma unroll
    for (int q = 0; q < NQ; ++q) {
      double s = 0.;
      for (int v = 0; v < 16; ++v) s += sred[v][q];
      Q[q] = s;
    }
    const double n = (double)(T_LEN - 1), Bn = (double)B_ROWS;
    // Q[0] = SP over ALL elements; SP excluding last column = Q[0]-Q[5].
    const double FA = Q[3] / Bn;
    const double FS3 = (Q[5] - (Q[0] - Q[5]) / n) / Bn;
    const double FS4 = 0.5 * (Q[4] + Q[1]) / Bn;
    const double FS6 = Q[1] / Bn;
    const double FS8 = Q[2] / Bn;
    const double o = FA * FA + FS3 * FS3 + FS4 * FS4 + FS6 * FS6 + FS8 * FS8;
    out[0] = (float)o;
  }
}

extern "C" void kernel_launch(void* const* d_in, const int* in_sizes, int n_in,
                              void* d_out, int out_size, void* d_ws, size_t ws_size,
                              hipStream_t stream) {
  const float* real = (const float*)d_in[0];
  const float* gen = (const float*)d_in[1];
  double* P = (double*)d_ws;            // NQ * NBLK * 8 = 96 KB
  float* out = (float*)d_out;

  sig_fstream<<<NBLK, 256, 0, stream>>>(real, gen, P);
  sig_final<<<1, 1024, 0, stream>>>(P, out);
}